// Round 1
// baseline (715.689 us; speedup 1.0000x reference)
//
#include <hip/hip_runtime.h>

typedef __attribute__((ext_vector_type(8))) short short8;   // 8 bf16 in 4 VGPRs (MFMA A/B frag)
typedef __attribute__((ext_vector_type(4))) float f32x4;    // MFMA C/D frag

#define MFMA16(a, b, c) __builtin_amdgcn_mfma_f32_16x16x32_bf16((a), (b), (c), 0, 0, 0)

// fp32 -> bf16, round-to-nearest-even (inputs are finite; no NaN handling needed)
static __device__ inline short f2bf(float x) {
    union { float f; unsigned u; } v;
    v.f = x;
    unsigned r = v.u + 0x7fffu + ((v.u >> 16) & 1u);
    return (short)(r >> 16);
}

// B=512, E=4, N=256, F=64
// out[b,n,g] = sum_e adj[b,e] @ (node[b] @ W_e + b_e) + node[b] @ W_add + b_add
__global__ __launch_bounds__(256, 2) void gconv_kernel(
    const float* __restrict__ node,    // [512,256,64]
    const float* __restrict__ adj,     // [512,4,256,256]
    const float* __restrict__ W_edge,  // [4,64,64]
    const float* __restrict__ b_edge,  // [4,64]
    const float* __restrict__ W_add,   // [64,64]
    const float* __restrict__ b_add,   // [64]
    float* __restrict__ out)           // [512,256,64]
{
    constexpr int N = 256, F = 64, E = 4;

    // Pads: node/wT rows +8 (stride 72 -> 36 dwords -> 2-way bank alias, free);
    // hiddenT rows 256+8=264 (132 dwords -> 2-way alias, free).
    __shared__ short node_bf[N][F + 8];      // node[b] in bf16            36864 B
    __shared__ short hiddenT[F][N + 8];      // hidden_e^T [g][m]          33792 B
    __shared__ short wT[F][F + 8];           // current weight^T [g][f]     9216 B
                                             // total 79872 B -> 2 blocks/CU
    const int b    = blockIdx.x;
    const int t    = threadIdx.x;
    const int lane = t & 63;
    const int w    = t >> 6;        // wave 0..3: rows 64w..64w+63 of C
    const int col  = lane & 15;     // MFMA: A-row / B-col / D-col within 16-tile
    const int kq   = lane >> 4;     // MFMA quad: k-offset 8*kq, D-rows 4*kq..4*kq+3

    // ---- stage node[b] fp32 -> bf16 LDS (coalesced float4) ----
    const float* nodeB = node + (size_t)b * (N * F);
    #pragma unroll
    for (int i = 0; i < 16; ++i) {
        int idx = i * 1024 + t * 4;
        float4 v = *(const float4*)(nodeB + idx);
        int r = idx >> 6, c = idx & 63;
        short4 s;
        s.x = f2bf(v.x); s.y = f2bf(v.y); s.z = f2bf(v.z); s.w = f2bf(v.w);
        *(short4*)&node_bf[r][c] = s;   // 8B aligned: 144*r + 2*c, c%4==0
    }
    // ---- stage W_add^T -> wT ----
    #pragma unroll
    for (int i = 0; i < 16; ++i) {
        int idx = i * 256 + t;
        wT[idx & 63][idx >> 6] = f2bf(W_add[idx]);
    }
    __syncthreads();

    // ---- residual: acc = node @ W_add (4x4 tiles of 16x16, K=64) ----
    f32x4 acc[4][4];
    {
        const f32x4 zf = {0.f, 0.f, 0.f, 0.f};
        #pragma unroll
        for (int rt = 0; rt < 4; ++rt)
            #pragma unroll
            for (int ct = 0; ct < 4; ++ct)
                acc[rt][ct] = zf;
        #pragma unroll
        for (int ks = 0; ks < 2; ++ks) {
            short8 afr[4], bfr[4];
            #pragma unroll
            for (int rt = 0; rt < 4; ++rt)
                afr[rt] = *(const short8*)&node_bf[64 * w + 16 * rt + col][32 * ks + 8 * kq];
            #pragma unroll
            for (int ct = 0; ct < 4; ++ct)
                bfr[ct] = *(const short8*)&wT[16 * ct + col][32 * ks + 8 * kq];
            #pragma unroll
            for (int rt = 0; rt < 4; ++rt)
                #pragma unroll
                for (int ct = 0; ct < 4; ++ct)
                    acc[rt][ct] = MFMA16(afr[rt], bfr[ct], acc[rt][ct]);
        }
    }
    __syncthreads();    // wT reads done before restage

    for (int e = 0; e < E; ++e) {
        // ---- stage W_edge[e]^T -> wT ----
        const float* We = W_edge + e * (F * F);
        #pragma unroll
        for (int i = 0; i < 16; ++i) {
            int idx = i * 256 + t;
            wT[idx & 63][idx >> 6] = f2bf(We[idx]);
        }
        __syncthreads();

        // ---- hidden_e = node @ W_e + b_e  -> hiddenT[g][m] (bf16) ----
        #pragma unroll
        for (int rt = 0; rt < 4; ++rt) {
            short8 a0 = *(const short8*)&node_bf[64 * w + 16 * rt + col][8 * kq];
            short8 a1 = *(const short8*)&node_bf[64 * w + 16 * rt + col][32 + 8 * kq];
            #pragma unroll
            for (int ct = 0; ct < 4; ++ct) {
                short8 b0 = *(const short8*)&wT[16 * ct + col][8 * kq];
                short8 b1 = *(const short8*)&wT[16 * ct + col][32 + 8 * kq];
                f32x4 h = {0.f, 0.f, 0.f, 0.f};
                h = MFMA16(a0, b0, h);
                h = MFMA16(a1, b1, h);
                float bias = b_edge[e * 64 + 16 * ct + col];
                short4 s;
                s.x = f2bf(h.x + bias); s.y = f2bf(h.y + bias);
                s.z = f2bf(h.z + bias); s.w = f2bf(h.w + bias);
                // D row = 4*kq + r -> m = 64w+16rt+4kq+r; 4 consecutive m -> one b64 write
                *(short4*)&hiddenT[16 * ct + col][64 * w + 16 * rt + 4 * kq] = s;
            }
        }
        __syncthreads();

        // ---- acc += adj[b,e] @ hidden_e   (K=256 in 8 steps of 32) ----
        const float* adjBase = adj + ((size_t)(b * 4 + e)) * (N * N);
        #pragma unroll 2
        for (int ks = 0; ks < 8; ++ks) {
            const int k0 = ks * 32 + 8 * kq;
            short8 afrag[4];
            #pragma unroll
            for (int rt = 0; rt < 4; ++rt) {
                const float* p = adjBase + (64 * w + 16 * rt + col) * 256 + k0;
                float4 v0 = *(const float4*)p;
                float4 v1 = *(const float4*)(p + 4);
                short8 a;
                a[0] = f2bf(v0.x); a[1] = f2bf(v0.y); a[2] = f2bf(v0.z); a[3] = f2bf(v0.w);
                a[4] = f2bf(v1.x); a[5] = f2bf(v1.y); a[6] = f2bf(v1.z); a[7] = f2bf(v1.w);
                afrag[rt] = a;
            }
            short8 bfrag[4];
            #pragma unroll
            for (int ct = 0; ct < 4; ++ct)
                bfrag[ct] = *(const short8*)&hiddenT[16 * ct + col][ks * 32 + 8 * kq];
            #pragma unroll
            for (int rt = 0; rt < 4; ++rt)
                #pragma unroll
                for (int ct = 0; ct < 4; ++ct)
                    acc[rt][ct] = MFMA16(afrag[rt], bfrag[ct], acc[rt][ct]);
        }
        __syncthreads();    // hiddenT reads done before next e overwrites
    }

    // ---- epilogue: out = acc + b_add ----
    float* outB = out + (size_t)b * (N * F);
    #pragma unroll
    for (int ct = 0; ct < 4; ++ct) {
        float bias = b_add[16 * ct + col];
        #pragma unroll
        for (int rt = 0; rt < 4; ++rt) {
            int row = 64 * w + 16 * rt + 4 * kq;
            #pragma unroll
            for (int r = 0; r < 4; ++r)
                outB[(size_t)(row + r) * 64 + 16 * ct + col] = acc[rt][ct][r] + bias;
        }
    }
}

extern "C" void kernel_launch(void* const* d_in, const int* in_sizes, int n_in,
                              void* d_out, int out_size, void* d_ws, size_t ws_size,
                              hipStream_t stream) {
    const float* node   = (const float*)d_in[0];
    const float* adj    = (const float*)d_in[1];
    const float* W_edge = (const float*)d_in[2];
    const float* b_edge = (const float*)d_in[3];
    const float* W_add  = (const float*)d_in[4];
    const float* b_add  = (const float*)d_in[5];
    float* out = (float*)d_out;

    gconv_kernel<<<dim3(512), dim3(256), 0, stream>>>(
        node, adj, W_edge, b_edge, W_add, b_add, out);
}

// Round 2
// 712.459 us; speedup vs baseline: 1.0045x; 1.0045x over previous
//
#include <hip/hip_runtime.h>

typedef __attribute__((ext_vector_type(8))) short short8;   // 8 bf16 (MFMA A/B frag)
typedef __attribute__((ext_vector_type(4))) float f32x4;    // MFMA C/D frag

#define MFMA16(a, b, c) __builtin_amdgcn_mfma_f32_16x16x32_bf16((a), (b), (c), 0, 0, 0)

// fp32 -> bf16 RNE
static __device__ inline short f2bf(float x) {
    union { float f; unsigned u; } v;
    v.f = x;
    unsigned r = v.u + 0x7fffu + ((v.u >> 16) & 1u);
    return (short)(r >> 16);
}
static __device__ inline short4 f2bf4(float4 v) {
    short4 s;
    s.x = f2bf(v.x); s.y = f2bf(v.y); s.z = f2bf(v.z); s.w = f2bf(v.w);
    return s;
}

// B=512, E=4, N=256, F=64
// out[b,n,g] = sum_e adj[b,e] @ (node[b] @ W_e + b_e) + node[b] @ W_add + b_add
__global__ __launch_bounds__(256, 2) void gconv_kernel(
    const float* __restrict__ node,    // [512,256,64]
    const float* __restrict__ adj,     // [512,4,256,256]
    const float* __restrict__ W_edge,  // [4,64,64]
    const float* __restrict__ b_edge,  // [4,64]
    const float* __restrict__ W_add,   // [64,64]
    const float* __restrict__ b_add,   // [64]
    float* __restrict__ out)           // [512,256,64]
{
    constexpr int E = 4;

    // adjL rows stride 72 bf16 = 36 dwords (≡4 mod 32: worst 8-way alias on a
    // minority of accesses — negligible vs global latency). hiddenT stride 264.
    __shared__ short adjL[256][72];      // adj k-tile, bf16      36864 B
    __shared__ short hiddenT[64][264];   // hidden_e^T [g][m]     33792 B
    __shared__ short wT[64][72];         // weight^T [g][f]        9216 B
                                         // total 79872 B -> 2 blocks/CU
    const int b    = blockIdx.x;
    const int t    = threadIdx.x;
    const int lane = t & 63;
    const int w    = t >> 6;        // wave 0..3: C rows 64w..64w+63
    const int col  = lane & 15;     // A-row / B-col / D-col in 16-tile
    const int kq   = lane >> 4;     // k-offset 8*kq; D-rows 4*kq..4*kq+3

    // ---- node[b] A-fragments -> registers (64 KB once; strided but tiny) ----
    const float* nodeB = node + (size_t)b * (256 * 64);
    short8 anode[4][2];
    #pragma unroll
    for (int rt = 0; rt < 4; ++rt)
        #pragma unroll
        for (int h = 0; h < 2; ++h) {
            const float* p = nodeB + (64 * w + 16 * rt + col) * 64 + 32 * h + 8 * kq;
            float4 v0 = *(const float4*)p;
            float4 v1 = *(const float4*)(p + 4);
            short8 a;
            a[0] = f2bf(v0.x); a[1] = f2bf(v0.y); a[2] = f2bf(v0.z); a[3] = f2bf(v0.w);
            a[4] = f2bf(v1.x); a[5] = f2bf(v1.y); a[6] = f2bf(v1.z); a[7] = f2bf(v1.w);
            anode[rt][h] = a;
        }

    // ---- stage W_add^T -> wT ----
    #pragma unroll
    for (int i = 0; i < 16; ++i) {
        int idx = i * 256 + t;
        wT[idx & 63][idx >> 6] = f2bf(W_add[idx]);
    }
    __syncthreads();

    // ---- residual: acc = node @ W_add ----
    f32x4 acc[4][4];
    {
        const f32x4 zf = {0.f, 0.f, 0.f, 0.f};
        #pragma unroll
        for (int rt = 0; rt < 4; ++rt)
            #pragma unroll
            for (int ct = 0; ct < 4; ++ct)
                acc[rt][ct] = zf;
        #pragma unroll
        for (int h = 0; h < 2; ++h) {
            short8 bfr[4];
            #pragma unroll
            for (int ct = 0; ct < 4; ++ct)
                bfr[ct] = *(const short8*)&wT[16 * ct + col][32 * h + 8 * kq];
            #pragma unroll
            for (int rt = 0; rt < 4; ++rt)
                #pragma unroll
                for (int ct = 0; ct < 4; ++ct)
                    acc[rt][ct] = MFMA16(anode[rt][h], bfr[ct], acc[rt][ct]);
        }
    }
    __syncthreads();    // wT reads done before e-loop restage

    for (int e = 0; e < E; ++e) {
        // ---- stage W_edge[e]^T -> wT ----
        const float* We = W_edge + e * (64 * 64);
        #pragma unroll
        for (int i = 0; i < 16; ++i) {
            int idx = i * 256 + t;
            wT[idx & 63][idx >> 6] = f2bf(We[idx]);
        }
        __syncthreads();

        // ---- hidden_e = node @ W_e + b_e  -> hiddenT[g][m] bf16 ----
        #pragma unroll
        for (int rt = 0; rt < 4; ++rt) {
            #pragma unroll
            for (int ct = 0; ct < 4; ++ct) {
                short8 b0 = *(const short8*)&wT[16 * ct + col][8 * kq];
                short8 b1 = *(const short8*)&wT[16 * ct + col][32 + 8 * kq];
                f32x4 h = {0.f, 0.f, 0.f, 0.f};
                h = MFMA16(anode[rt][0], b0, h);
                h = MFMA16(anode[rt][1], b1, h);
                float bias = b_edge[e * 64 + 16 * ct + col];
                short4 s;
                s.x = f2bf(h.x + bias); s.y = f2bf(h.y + bias);
                s.z = f2bf(h.z + bias); s.w = f2bf(h.w + bias);
                *(short4*)&hiddenT[16 * ct + col][64 * w + 16 * rt + 4 * kq] = s;
            }
        }
        __syncthreads();

        // ---- acc += adj[b,e] @ hidden_e : 4 k-tiles of 64, LDS-staged ----
        const float* adjE = adj + ((size_t)(b * 4 + e)) * (256 * 256);
        for (int kt = 0; kt < 4; ++kt) {
            // stage adj[:, 64kt..64kt+63] -> adjL, fully lane-contiguous:
            // per instr: 4 rows x 256 B contiguous each = 1 KB, all bytes used
            {
                const int c4  = t & 15;          // float4 index within row-chunk
                const int r0  = t >> 4;          // row group 0..15
                const float* base = adjE + kt * 64 + c4 * 4;
                #pragma unroll
                for (int i = 0; i < 16; ++i) {
                    int row = i * 16 + r0;
                    float4 v = *(const float4*)(base + row * 256);
                    *(short4*)&adjL[row][c4 * 4] = f2bf4(v);
                }
            }
            __syncthreads();

            #pragma unroll
            for (int ks2 = 0; ks2 < 2; ++ks2) {
                short8 afrag[4], bfrag[4];
                #pragma unroll
                for (int rt = 0; rt < 4; ++rt)
                    afrag[rt] = *(const short8*)&adjL[64 * w + 16 * rt + col][32 * ks2 + 8 * kq];
                #pragma unroll
                for (int ct = 0; ct < 4; ++ct)
                    bfrag[ct] = *(const short8*)&hiddenT[16 * ct + col][kt * 64 + 32 * ks2 + 8 * kq];
                #pragma unroll
                for (int rt = 0; rt < 4; ++rt)
                    #pragma unroll
                    for (int ct = 0; ct < 4; ++ct)
                        acc[rt][ct] = MFMA16(afrag[rt], bfrag[ct], acc[rt][ct]);
            }
            __syncthreads();    // adjL consumed before next stage; hiddenT safe
        }
    }

    // ---- epilogue: out = acc + b_add ----
    float* outB = out + (size_t)b * (256 * 64);
    #pragma unroll
    for (int ct = 0; ct < 4; ++ct) {
        float bias = b_add[16 * ct + col];
        #pragma unroll
        for (int rt = 0; rt < 4; ++rt) {
            int row = 64 * w + 16 * rt + 4 * kq;
            #pragma unroll
            for (int r = 0; r < 4; ++r)
                outB[(size_t)(row + r) * 64 + 16 * ct + col] = acc[rt][ct][r] + bias;
        }
    }
}

extern "C" void kernel_launch(void* const* d_in, const int* in_sizes, int n_in,
                              void* d_out, int out_size, void* d_ws, size_t ws_size,
                              hipStream_t stream) {
    const float* node   = (const float*)d_in[0];
    const float* adj    = (const float*)d_in[1];
    const float* W_edge = (const float*)d_in[2];
    const float* b_edge = (const float*)d_in[3];
    const float* W_add  = (const float*)d_in[4];
    const float* b_add  = (const float*)d_in[5];
    float* out = (float*)d_out;

    gconv_kernel<<<dim3(512), dim3(256), 0, stream>>>(
        node, adj, W_edge, b_edge, W_add, b_add, out);
}